// Round 6
// baseline (2705.636 us; speedup 1.0000x reference)
//
#include <hip/hip_runtime.h>

#define BATCH 32
#define NPTS  8192
#define DIM   64
#define KC    128
#define NITER 10
#define LN_EPS 1e-5f

#define PTS_PER_BLK 256
#define BLKS_PER_B  32   // NPTS / PTS_PER_BLK
#define NBLK        (BATCH * BLKS_PER_B)   // 1024

// ---------------------------------------------------------------------------
// Correctness invariants (rounds 2-5):
//  * distance d = (x2 + c2[k]) - 2*dot in fp32, accumulation order of the
//    thrice-passing round-3 kernel (d0..d3 by j%4, .x.y.z.w within) — all
//    fp32 same-formula implementations make correlated boundary decisions.
//  * center sums: f32 LDS atomics + per-block partial flush + fp64 cross-
//    block reduce (R4-proven REPLAY-STABLE; R5's pin/scan diverged on replay
//    and is reverted wholesale).
//  * x routed global->LDS->regs: identical bits, so trajectory unchanged.
//
// d_out doubles as storage: centers region = cen; soft region temporarily
// holds per-block partials (fully overwritten by final_kernel).
// ws: xn fp32 (64MB) | c2 fp32 (16KB)
// ---------------------------------------------------------------------------

// x lives in LDS transposed: float4 chunk j of point (thread) p at
// xs4[j*256 + p]  (byte offset j*4096 + p*16 -> ds_read_b128 base+imm).
#define DOTL(res, cc) do {                                                 \
    float _d0 = 0.f, _d1 = 0.f, _d2 = 0.f, _d3 = 0.f;                      \
    _Pragma("unroll")                                                      \
    for (int _j = 0; _j < 16; ++_j) {                                      \
        float4 _xv = xs4[_j * PTS_PER_BLK + tid];                          \
        float4 _cv = (cc)[_j];                                             \
        float& _a = (_j & 3) == 0 ? _d0 : (_j & 3) == 1 ? _d1              \
                    : (_j & 3) == 2 ? _d2 : _d3;                           \
        _a = fmaf(_xv.w, _cv.w, fmaf(_xv.z, _cv.z,                         \
             fmaf(_xv.y, _cv.y, fmaf(_xv.x, _cv.x, _a))));                 \
    }                                                                      \
    res = (_d0 + _d1) + (_d2 + _d3);                                       \
} while (0)

// One wave per row (unchanged from passing rounds).
__global__ __launch_bounds__(256) void ln_kernel(const float* __restrict__ patches,
                                                 const float* __restrict__ gamma,
                                                 const float* __restrict__ beta,
                                                 float* __restrict__ xn,
                                                 float* __restrict__ cen,
                                                 float* __restrict__ c2) {
    int row = blockIdx.x * 4 + (threadIdx.x >> 6);
    int lane = threadIdx.x & 63;
    size_t base = (size_t)row * DIM + lane;
    float x = patches[base];

    float s = x;
#pragma unroll
    for (int m = 32; m >= 1; m >>= 1) s += __shfl_xor(s, m, 64);
    float mu = s * (1.0f / 64.0f);
    float dx = x - mu;

    float v = dx * dx;
#pragma unroll
    for (int m = 32; m >= 1; m >>= 1) v += __shfl_xor(v, m, 64);
    float var = v * (1.0f / 64.0f);

    float val = dx * (1.0f / sqrtf(var + LN_EPS)) * gamma[lane] + beta[lane];
    xn[base] = val;

    int n = row & (NPTS - 1);
    int b = row >> 13;  // NPTS = 8192 = 2^13
    if (n < KC) {
        cen[((size_t)(b * KC + n)) * DIM + lane] = val;
        float q = val * val;
#pragma unroll
        for (int m = 32; m >= 1; m >>= 1) q += __shfl_xor(q, m, 64);
        if (lane == 0) c2[b * KC + n] = q;
    }
}

// Phase A: stage x -> LDS (transposed) + xsq.  Phase B: argmin, x from LDS
// (compiler cannot rematerialize; LDS BW 64cyc/k/CU << 256cyc VALU).
// Phase C: overlay dead xs with pad-65 accumulator, zero.  Phase D: R4-proven
// f32 LDS atomics (x re-read from global, identical bits).  Phase E: flush.
__global__ __launch_bounds__(PTS_PER_BLK) void assign_kernel(const float* __restrict__ xn,
                                                             const float* __restrict__ cen,
                                                             const float* __restrict__ c2,
                                                             float* __restrict__ part,
                                                             float* __restrict__ cntpart) {
    __shared__ __align__(16) char smem[65536];
    float4* xs4 = (float4*)smem;                  // [16][256] float4 = 64KB
    float* accf = (float*)smem;                   // overlay: [128][65] f32
    float* cntf = (float*)(smem + 33280);         // overlay: [128] f32

    int tid = threadIdx.x;
    int blk = blockIdx.x;
    int b = blk >> 5;                              // 32 blocks per batch
    int pbase = b * NPTS + ((blk & 31) << 8);
    int p = pbase + tid;

    // Phase A: stage + xsq (same accumulation order as round-3 sq64)
    const float4* xp = (const float4*)(xn + (size_t)p * DIM);
    float a0 = 0.f, a1 = 0.f, a2 = 0.f, a3 = 0.f;
#pragma unroll
    for (int j = 0; j < 16; ++j) {
        float4 t = xp[j];
        xs4[j * PTS_PER_BLK + tid] = t;
        a0 = fmaf(t.x, t.x, a0);
        a1 = fmaf(t.y, t.y, a1);
        a2 = fmaf(t.z, t.z, a2);
        a3 = fmaf(t.w, t.w, a3);
    }
    float xsq = (a0 + a1) + (a2 + a3);
    __syncthreads();

    const float4* cp = (const float4*)(cen + (size_t)b * KC * DIM);
    const float* c2p = c2 + b * KC;

    // Phase B: argmin (distance bits identical to rounds 3/4)
    float best = 3.4e38f;
    int bi = 0;
    for (int k = 0; k < KC; ++k) {
        float dot;
        DOTL(dot, cp + k * 16);
        float t = xsq + c2p[k];
        float d = t - 2.0f * dot;
        if (d < best) { best = d; bi = k; }  // strict < == argmin first-index
    }
    __syncthreads();  // all reads of xs done before overlay

    // Phase C: zero accumulator + counts
    for (int i = tid; i < KC * 65; i += PTS_PER_BLK) accf[i] = 0.f;
    if (tid < KC) cntf[tid] = 0.f;
    __syncthreads();

    // Phase D: f32 LDS atomics (R4-proven). x re-read from global: same bits.
    {
        float* dst = accf + bi * 65;
#pragma unroll
        for (int j = 0; j < 16; ++j) {
            float4 t = xp[j];
            atomicAdd(dst + 4 * j + 0, t.x);
            atomicAdd(dst + 4 * j + 1, t.y);
            atomicAdd(dst + 4 * j + 2, t.z);
            atomicAdd(dst + 4 * j + 3, t.w);
        }
        atomicAdd(&cntf[bi], 1.0f);
    }
    __syncthreads();

    // Phase E: flush per-block partials
    float* gp = part + (size_t)blk * (KC * DIM);
    for (int i = tid; i < KC * DIM; i += PTS_PER_BLK) {
        int k = i >> 6, d = i & 63;
        gp[i] = accf[k * 65 + d];
    }
    if (tid < KC) cntpart[blk * KC + tid] = cntf[tid];
}

// One wave per (b,k): fp64 reduce of 32 f32 block partials -> fp32 center+norm.
__global__ __launch_bounds__(256) void update_kernel(const float* __restrict__ part,
                                                     const float* __restrict__ cntpart,
                                                     float* __restrict__ cen,
                                                     float* __restrict__ c2) {
    int row = blockIdx.x * 4 + (threadIdx.x >> 6);  // b*KC + k
    int lane = threadIdx.x & 63;
    int b = row >> 7;
    int k = row & (KC - 1);

    double s = 0.0;
    float cnt = 0.f;
#pragma unroll
    for (int sub = 0; sub < BLKS_PER_B; ++sub) {
        s += (double)part[((size_t)(b * BLKS_PER_B + sub)) * (KC * DIM) + (size_t)k * DIM + lane];
        cnt += cntpart[(b * BLKS_PER_B + sub) * KC + k];
    }

    size_t idx = (size_t)row * DIM + lane;
    float old = cen[idx];
    float nc = (cnt > 0.f) ? ((float)s / cnt) : old;
    cen[idx] = nc;

    float q = nc * nc;
#pragma unroll
    for (int m = 32; m >= 1; m >>= 1) q += __shfl_xor(q, m, 64);
    if (lane == 0) c2[row] = q;
}

// Same LDS-x staging; pass 1 online max+denominator, pass 2 compute + float4
// stores (R4-proven write scheme). Distance formula/order unchanged.
__global__ __launch_bounds__(PTS_PER_BLK) void final_kernel(const float* __restrict__ xn,
                                                            const float* __restrict__ cen,
                                                            const float* __restrict__ c2,
                                                            float* __restrict__ soft) {
    __shared__ __align__(16) char smem[65536];
    float4* xs4 = (float4*)smem;

    int tid = threadIdx.x;
    int blk = blockIdx.x;
    int b = blk >> 5;
    int pbase = b * NPTS + ((blk & 31) << 8);
    int p = pbase + tid;

    const float4* xp = (const float4*)(xn + (size_t)p * DIM);
    float a0 = 0.f, a1 = 0.f, a2 = 0.f, a3 = 0.f;
#pragma unroll
    for (int j = 0; j < 16; ++j) {
        float4 t = xp[j];
        xs4[j * PTS_PER_BLK + tid] = t;
        a0 = fmaf(t.x, t.x, a0);
        a1 = fmaf(t.y, t.y, a1);
        a2 = fmaf(t.z, t.z, a2);
        a3 = fmaf(t.w, t.w, a3);
    }
    float xsq = (a0 + a1) + (a2 + a3);
    __syncthreads();

    const float4* cp = (const float4*)(cen + (size_t)b * KC * DIM);
    const float* c2p = c2 + b * KC;

    float m = -3.4e38f;
    float ssum = 0.f;
    for (int k = 0; k < KC; ++k) {
        float dot;
        DOTL(dot, cp + k * 16);
        float t = xsq + c2p[k];
        float z = -(t - 2.0f * dot);
        if (z > m) {
            ssum = ssum * __expf(m - z) + 1.0f;
            m = z;
        } else {
            ssum += __expf(z - m);
        }
    }
    float rinv = 1.0f / ssum;

    float4* op = (float4*)(soft + (size_t)p * KC);
    for (int kb = 0; kb < KC / 4; ++kb) {
        float e[4];
#pragma unroll
        for (int u = 0; u < 4; ++u) {
            int k = kb * 4 + u;
            float dot;
            DOTL(dot, cp + k * 16);
            float t = xsq + c2p[k];
            float z = -(t - 2.0f * dot);
            e[u] = __expf(z - m) * rinv;
        }
        op[kb] = make_float4(e[0], e[1], e[2], e[3]);
    }
}

extern "C" void kernel_launch(void* const* d_in, const int* in_sizes, int n_in,
                              void* d_out, int out_size, void* d_ws, size_t ws_size,
                              hipStream_t stream) {
    (void)in_sizes; (void)n_in; (void)out_size; (void)ws_size;
    const float* patches = (const float*)d_in[0];
    const float* gamma = (const float*)d_in[1];
    const float* beta = (const float*)d_in[2];
    float* out = (float*)d_out;

    float* ws = (float*)d_ws;
    float* xn = ws;                                   // 16,777,216 f32
    float* c2 = xn + (size_t)BATCH * NPTS * DIM;      // 4,096 f32

    float* cen = out;                                 // centers live in d_out
    float* soft = out + (size_t)BATCH * KC * DIM;
    float* part = soft;                               // 1024*8192 f32 (temp)
    float* cntpart = part + (size_t)NBLK * KC * DIM;  // 1024*128 f32 (temp)

    ln_kernel<<<BATCH * NPTS / 4, 256, 0, stream>>>(patches, gamma, beta, xn, cen, c2);

    for (int it = 0; it < NITER; ++it) {
        assign_kernel<<<NBLK, PTS_PER_BLK, 0, stream>>>(xn, cen, c2, part, cntpart);
        update_kernel<<<BATCH * KC / 4, 256, 0, stream>>>(part, cntpart, cen, c2);
    }

    final_kernel<<<NBLK, PTS_PER_BLK, 0, stream>>>(xn, cen, c2, soft);
}

// Round 7
// 2657.963 us; speedup vs baseline: 1.0179x; 1.0179x over previous
//
#include <hip/hip_runtime.h>

#define BATCH 32
#define NPTS  8192
#define DIM   64
#define KC    128
#define NITER 10
#define LN_EPS 1e-5f

#define PTS_PER_BLK 256
#define BLKS_PER_B  32   // NPTS / PTS_PER_BLK
#define NBLK        (BATCH * BLKS_PER_B)   // 1024

// ---------------------------------------------------------------------------
// Correctness invariants (rounds 2-6):
//  * distance d = (x2 + c2[k]) - 2*dot in fp32, accumulation order of the
//    thrice-passing round-3 kernel: per k, 4 sub-accumulators indexed by
//    d-chunk j&3 (j ascending), FMA nesting .x.y.z.w, final (d0+d1)+(d2+d3).
//  * center sums: f32 LDS atomics + per-block partial flush + fp64 cross-
//    block reduce (R4/R6-proven replay-stable).
//  * x routed global->LDS->regs: identical bits, trajectory unchanged.
//
// R6 lesson: per-k x-access is the disease (L1/remat/LDS all too slow).
// Fix: GEMM register tiling. k-tile of 8 with 32 register accumulators;
// each x d-chunk is read ONCE per tile and amortized over 8 k's ->
// LDS traffic drops 16x, kernel becomes VALU-bound.
//
// d_out doubles as storage: centers region = cen; soft region temporarily
// holds per-block partials (fully overwritten by final_kernel).
// ws: xn fp32 (64MB) | c2 fp32 (16KB)
// ---------------------------------------------------------------------------

// One k-tile of 8: for each d-chunk j, read x once (LDS), FMA into the
// tile's 8x4 sub-accumulators. Bit-identical per-k arithmetic to round 3.
// Emits: dot8[0..7]
#define DOT_TILE8(dot8, kt) do {                                           \
    float _d0[8], _d1[8], _d2[8], _d3[8];                                  \
    _Pragma("unroll")                                                      \
    for (int _u = 0; _u < 8; ++_u) {                                       \
        _d0[_u] = 0.f; _d1[_u] = 0.f; _d2[_u] = 0.f; _d3[_u] = 0.f;        \
    }                                                                      \
    const float4* _ct = cp + (size_t)(kt) * 16;                            \
    _Pragma("unroll")                                                      \
    for (int _j = 0; _j < 16; ++_j) {                                      \
        float4 _xv = xs4[_j * PTS_PER_BLK + tid];                          \
        _Pragma("unroll")                                                  \
        for (int _u = 0; _u < 8; ++_u) {                                   \
            float4 _cv = _ct[_u * 16 + _j];                                \
            float& _a = (_j & 3) == 0 ? _d0[_u] : (_j & 3) == 1 ? _d1[_u]  \
                        : (_j & 3) == 2 ? _d2[_u] : _d3[_u];               \
            _a = fmaf(_xv.w, _cv.w, fmaf(_xv.z, _cv.z,                     \
                 fmaf(_xv.y, _cv.y, fmaf(_xv.x, _cv.x, _a))));             \
        }                                                                  \
    }                                                                      \
    _Pragma("unroll")                                                      \
    for (int _u = 0; _u < 8; ++_u)                                         \
        dot8[_u] = (_d0[_u] + _d1[_u]) + (_d2[_u] + _d3[_u]);              \
} while (0)

// One wave per row (unchanged from passing rounds).
__global__ __launch_bounds__(256) void ln_kernel(const float* __restrict__ patches,
                                                 const float* __restrict__ gamma,
                                                 const float* __restrict__ beta,
                                                 float* __restrict__ xn,
                                                 float* __restrict__ cen,
                                                 float* __restrict__ c2) {
    int row = blockIdx.x * 4 + (threadIdx.x >> 6);
    int lane = threadIdx.x & 63;
    size_t base = (size_t)row * DIM + lane;
    float x = patches[base];

    float s = x;
#pragma unroll
    for (int m = 32; m >= 1; m >>= 1) s += __shfl_xor(s, m, 64);
    float mu = s * (1.0f / 64.0f);
    float dx = x - mu;

    float v = dx * dx;
#pragma unroll
    for (int m = 32; m >= 1; m >>= 1) v += __shfl_xor(v, m, 64);
    float var = v * (1.0f / 64.0f);

    float val = dx * (1.0f / sqrtf(var + LN_EPS)) * gamma[lane] + beta[lane];
    xn[base] = val;

    int n = row & (NPTS - 1);
    int b = row >> 13;  // NPTS = 8192 = 2^13
    if (n < KC) {
        cen[((size_t)(b * KC + n)) * DIM + lane] = val;
        float q = val * val;
#pragma unroll
        for (int m = 32; m >= 1; m >>= 1) q += __shfl_xor(q, m, 64);
        if (lane == 0) c2[b * KC + n] = q;
    }
}

// Phase A: stage x -> LDS (transposed) + xsq.  Phase B: k-tiled argmin
// (x chunk read once per 8 k's -> VALU-bound).  Phase C: overlay dead xs
// with pad-65 accumulator.  Phase D: f32 LDS atomics (x re-read from
// global, identical bits).  Phase E: flush.
__global__ __launch_bounds__(PTS_PER_BLK) void assign_kernel(const float* __restrict__ xn,
                                                             const float* __restrict__ cen,
                                                             const float* __restrict__ c2,
                                                             float* __restrict__ part,
                                                             float* __restrict__ cntpart) {
    __shared__ __align__(16) char smem[65536];
    float4* xs4 = (float4*)smem;                  // [16][256] float4 = 64KB
    float* accf = (float*)smem;                   // overlay: [128][65] f32
    float* cntf = (float*)(smem + 33280);         // overlay: [128] f32

    int tid = threadIdx.x;
    int blk = blockIdx.x;
    int b = blk >> 5;                              // 32 blocks per batch
    int pbase = b * NPTS + ((blk & 31) << 8);
    int p = pbase + tid;

    // Phase A: stage + xsq (same accumulation order as round-3 sq64)
    const float4* xp = (const float4*)(xn + (size_t)p * DIM);
    float a0 = 0.f, a1 = 0.f, a2 = 0.f, a3 = 0.f;
#pragma unroll
    for (int j = 0; j < 16; ++j) {
        float4 t = xp[j];
        xs4[j * PTS_PER_BLK + tid] = t;
        a0 = fmaf(t.x, t.x, a0);
        a1 = fmaf(t.y, t.y, a1);
        a2 = fmaf(t.z, t.z, a2);
        a3 = fmaf(t.w, t.w, a3);
    }
    float xsq = (a0 + a1) + (a2 + a3);
    __syncthreads();

    const float4* cp = (const float4*)(cen + (size_t)b * KC * DIM);
    const float* c2p = c2 + b * KC;

    // Phase B: k-tiled argmin (bit-identical distance arithmetic)
    float best = 3.4e38f;
    int bi = 0;
    for (int kt = 0; kt < KC; kt += 8) {
        float dot8[8];
        DOT_TILE8(dot8, kt);
#pragma unroll
        for (int u = 0; u < 8; ++u) {
            float t = xsq + c2p[kt + u];
            float d = t - 2.0f * dot8[u];
            if (d < best) { best = d; bi = kt + u; }  // strict < = first index
        }
    }
    __syncthreads();  // all reads of xs done before overlay

    // Phase C: zero accumulator + counts
    for (int i = tid; i < KC * 65; i += PTS_PER_BLK) accf[i] = 0.f;
    if (tid < KC) cntf[tid] = 0.f;
    __syncthreads();

    // Phase D: f32 LDS atomics (R4/R6-proven). x re-read from global: same bits.
    {
        float* dst = accf + bi * 65;
#pragma unroll
        for (int j = 0; j < 16; ++j) {
            float4 t = xp[j];
            atomicAdd(dst + 4 * j + 0, t.x);
            atomicAdd(dst + 4 * j + 1, t.y);
            atomicAdd(dst + 4 * j + 2, t.z);
            atomicAdd(dst + 4 * j + 3, t.w);
        }
        atomicAdd(&cntf[bi], 1.0f);
    }
    __syncthreads();

    // Phase E: flush per-block partials
    float* gp = part + (size_t)blk * (KC * DIM);
    for (int i = tid; i < KC * DIM; i += PTS_PER_BLK) {
        int k = i >> 6, d = i & 63;
        gp[i] = accf[k * 65 + d];
    }
    if (tid < KC) cntpart[blk * KC + tid] = cntf[tid];
}

// One wave per (b,k): fp64 reduce of 32 f32 block partials -> fp32 center+norm.
__global__ __launch_bounds__(256) void update_kernel(const float* __restrict__ part,
                                                     const float* __restrict__ cntpart,
                                                     float* __restrict__ cen,
                                                     float* __restrict__ c2) {
    int row = blockIdx.x * 4 + (threadIdx.x >> 6);  // b*KC + k
    int lane = threadIdx.x & 63;
    int b = row >> 7;
    int k = row & (KC - 1);

    double s = 0.0;
    float cnt = 0.f;
#pragma unroll
    for (int sub = 0; sub < BLKS_PER_B; ++sub) {
        s += (double)part[((size_t)(b * BLKS_PER_B + sub)) * (KC * DIM) + (size_t)k * DIM + lane];
        cnt += cntpart[(b * BLKS_PER_B + sub) * KC + k];
    }

    size_t idx = (size_t)row * DIM + lane;
    float old = cen[idx];
    float nc = (cnt > 0.f) ? ((float)s / cnt) : old;
    cen[idx] = nc;

    float q = nc * nc;
#pragma unroll
    for (int m = 32; m >= 1; m >>= 1) q += __shfl_xor(q, m, 64);
    if (lane == 0) c2[row] = q;
}

// Same LDS-x staging + k-tiling; pass 1 online max+denominator (k ascending,
// same online ops as passing rounds), pass 2 compute + float4 stores.
__global__ __launch_bounds__(PTS_PER_BLK) void final_kernel(const float* __restrict__ xn,
                                                            const float* __restrict__ cen,
                                                            const float* __restrict__ c2,
                                                            float* __restrict__ soft) {
    __shared__ __align__(16) char smem[65536];
    float4* xs4 = (float4*)smem;

    int tid = threadIdx.x;
    int blk = blockIdx.x;
    int b = blk >> 5;
    int pbase = b * NPTS + ((blk & 31) << 8);
    int p = pbase + tid;

    const float4* xp = (const float4*)(xn + (size_t)p * DIM);
    float a0 = 0.f, a1 = 0.f, a2 = 0.f, a3 = 0.f;
#pragma unroll
    for (int j = 0; j < 16; ++j) {
        float4 t = xp[j];
        xs4[j * PTS_PER_BLK + tid] = t;
        a0 = fmaf(t.x, t.x, a0);
        a1 = fmaf(t.y, t.y, a1);
        a2 = fmaf(t.z, t.z, a2);
        a3 = fmaf(t.w, t.w, a3);
    }
    float xsq = (a0 + a1) + (a2 + a3);
    __syncthreads();

    const float4* cp = (const float4*)(cen + (size_t)b * KC * DIM);
    const float* c2p = c2 + b * KC;

    float m = -3.4e38f;
    float ssum = 0.f;
    for (int kt = 0; kt < KC; kt += 8) {
        float dot8[8];
        DOT_TILE8(dot8, kt);
#pragma unroll
        for (int u = 0; u < 8; ++u) {
            float t = xsq + c2p[kt + u];
            float z = -(t - 2.0f * dot8[u]);
            if (z > m) {
                ssum = ssum * __expf(m - z) + 1.0f;
                m = z;
            } else {
                ssum += __expf(z - m);
            }
        }
    }
    float rinv = 1.0f / ssum;

    float4* op = (float4*)(soft + (size_t)p * KC);
    for (int kt = 0; kt < KC; kt += 8) {
        float dot8[8];
        DOT_TILE8(dot8, kt);
        float e[8];
#pragma unroll
        for (int u = 0; u < 8; ++u) {
            float t = xsq + c2p[kt + u];
            float z = -(t - 2.0f * dot8[u]);
            e[u] = __expf(z - m) * rinv;
        }
        op[kt / 4 + 0] = make_float4(e[0], e[1], e[2], e[3]);
        op[kt / 4 + 1] = make_float4(e[4], e[5], e[6], e[7]);
    }
}

extern "C" void kernel_launch(void* const* d_in, const int* in_sizes, int n_in,
                              void* d_out, int out_size, void* d_ws, size_t ws_size,
                              hipStream_t stream) {
    (void)in_sizes; (void)n_in; (void)out_size; (void)ws_size;
    const float* patches = (const float*)d_in[0];
    const float* gamma = (const float*)d_in[1];
    const float* beta = (const float*)d_in[2];
    float* out = (float*)d_out;

    float* ws = (float*)d_ws;
    float* xn = ws;                                   // 16,777,216 f32
    float* c2 = xn + (size_t)BATCH * NPTS * DIM;      // 4,096 f32

    float* cen = out;                                 // centers live in d_out
    float* soft = out + (size_t)BATCH * KC * DIM;
    float* part = soft;                               // 1024*8192 f32 (temp)
    float* cntpart = part + (size_t)NBLK * KC * DIM;  // 1024*128 f32 (temp)

    ln_kernel<<<BATCH * NPTS / 4, 256, 0, stream>>>(patches, gamma, beta, xn, cen, c2);

    for (int it = 0; it < NITER; ++it) {
        assign_kernel<<<NBLK, PTS_PER_BLK, 0, stream>>>(xn, cen, c2, part, cntpart);
        update_kernel<<<BATCH * KC / 4, 256, 0, stream>>>(part, cntpart, cen, c2);
    }

    final_kernel<<<NBLK, PTS_PER_BLK, 0, stream>>>(xn, cen, c2, soft);
}

// Round 8
// 2527.299 us; speedup vs baseline: 1.0706x; 1.0517x over previous
//
#include <hip/hip_runtime.h>

#define BATCH 32
#define NPTS  8192
#define DIM   64
#define KC    128
#define NITER 10
#define LN_EPS 1e-5f

#define BLKS_PER_B  32   // 256 points per block
#define NBLK        (BATCH * BLKS_PER_B)   // 1024

// ---------------------------------------------------------------------------
// Layout change (R7 lesson): EVERY prior round re-fetched an operand per k.
// Now: lane l owns clusters {2l, 2l+1}; c rows live in 128 VGPRs for the
// whole pass; x rows stream via wave-uniform s_loads (SMEM pipe). Inner loop
// has ZERO vector-memory ops -> VALU-bound even at 2 waves/SIMD.
//
// Correctness invariants (unchanged trajectory vs passing R6):
//  * d = (x2 + c2[k]) - 2*dot, fp32, same per-k accumulation order (4 sub-acc
//    by j&3, .x.y.z.w nesting, (e0+e1)+(e2+e3)); 2*dot exact (x2 never rounds).
//  * xsq hoisted (loop-invariant) with BIT-IDENTICAL op order to R6 Phase A.
//  * argmin: butterfly with (d, k) lexicographic comparator == serial
//    first-index scan for identical d bits.
//  * center sums: f32 LDS atomics + per-block flush + fp64 reduce (R6-proven).
//
// d_out doubles as storage: centers region = cen; soft region temporarily
// holds per-block partials (fully overwritten by final_kernel).
// ws: xn fp32 (64MB) | xsq fp32 (1MB) | c2 fp32 (16KB)
// ---------------------------------------------------------------------------

// dot of s_load'd x (xs_[64], uniform) with per-lane c row; bit-identical
// accumulation order to the passing rounds.
#define DOT_SC(res, c) do {                                                 \
    float e0 = 0.f, e1 = 0.f, e2 = 0.f, e3 = 0.f;                           \
    _Pragma("unroll")                                                       \
    for (int j = 0; j < 16; ++j) {                                          \
        float t = (j & 3) == 0 ? e0 : (j & 3) == 1 ? e1                     \
                  : (j & 3) == 2 ? e2 : e3;                                 \
        t = fmaf(xs_[4 * j + 0], (c)[4 * j + 0], t);                        \
        t = fmaf(xs_[4 * j + 1], (c)[4 * j + 1], t);                        \
        t = fmaf(xs_[4 * j + 2], (c)[4 * j + 2], t);                        \
        t = fmaf(xs_[4 * j + 3], (c)[4 * j + 3], t);                        \
        if ((j & 3) == 0) e0 = t; else if ((j & 3) == 1) e1 = t;            \
        else if ((j & 3) == 2) e2 = t; else e3 = t;                         \
    }                                                                       \
    res = (e0 + e1) + (e2 + e3);                                            \
} while (0)

#define LOAD_C2ROWS()                                                       \
    int kA = 2 * lane, kB = 2 * lane + 1;                                   \
    const float* cb = cen + (size_t)b * KC * DIM;                           \
    float cA[64], cB[64];                                                   \
    _Pragma("unroll")                                                       \
    for (int j = 0; j < 16; ++j) {                                          \
        float4 t = ((const float4*)(cb + (size_t)kA * DIM))[j];             \
        cA[4*j] = t.x; cA[4*j+1] = t.y; cA[4*j+2] = t.z; cA[4*j+3] = t.w;   \
        float4 u = ((const float4*)(cb + (size_t)kB * DIM))[j];             \
        cB[4*j] = u.x; cB[4*j+1] = u.y; cB[4*j+2] = u.z; cB[4*j+3] = u.w;   \
    }                                                                       \
    float c2A = c2[b * KC + kA], c2B = c2[b * KC + kB]

#define LOAD_XS(xrow)                                                       \
    float xs_[64];                                                          \
    _Pragma("unroll")                                                       \
    for (int j = 0; j < 64; ++j) xs_[j] = (xrow)[j]

// One wave per row (unchanged from passing rounds).
__global__ __launch_bounds__(256) void ln_kernel(const float* __restrict__ patches,
                                                 const float* __restrict__ gamma,
                                                 const float* __restrict__ beta,
                                                 float* __restrict__ xn,
                                                 float* __restrict__ cen,
                                                 float* __restrict__ c2) {
    int row = blockIdx.x * 4 + (threadIdx.x >> 6);
    int lane = threadIdx.x & 63;
    size_t base = (size_t)row * DIM + lane;
    float x = patches[base];

    float s = x;
#pragma unroll
    for (int m = 32; m >= 1; m >>= 1) s += __shfl_xor(s, m, 64);
    float mu = s * (1.0f / 64.0f);
    float dx = x - mu;

    float v = dx * dx;
#pragma unroll
    for (int m = 32; m >= 1; m >>= 1) v += __shfl_xor(v, m, 64);
    float var = v * (1.0f / 64.0f);

    float val = dx * (1.0f / sqrtf(var + LN_EPS)) * gamma[lane] + beta[lane];
    xn[base] = val;

    int n = row & (NPTS - 1);
    int b = row >> 13;  // NPTS = 8192 = 2^13
    if (n < KC) {
        cen[((size_t)(b * KC + n)) * DIM + lane] = val;
        float q = val * val;
#pragma unroll
        for (int m = 32; m >= 1; m >>= 1) q += __shfl_xor(q, m, 64);
        if (lane == 0) c2[b * KC + n] = q;
    }
}

// One-time: xsq[p], bit-identical op order to R6's per-pass computation.
__global__ __launch_bounds__(256) void xsq_kernel(const float* __restrict__ xn,
                                                  float* __restrict__ xsq) {
    int p = blockIdx.x * 256 + threadIdx.x;
    const float4* xp = (const float4*)(xn + (size_t)p * DIM);
    float a0 = 0.f, a1 = 0.f, a2 = 0.f, a3 = 0.f;
#pragma unroll
    for (int j = 0; j < 16; ++j) {
        float4 t = xp[j];
        a0 = fmaf(t.x, t.x, a0);
        a1 = fmaf(t.y, t.y, a1);
        a2 = fmaf(t.z, t.z, a2);
        a3 = fmaf(t.w, t.w, a3);
    }
    xsq[p] = (a0 + a1) + (a2 + a3);
}

// Wave covers all 128 k (2 per lane, c in VGPRs); points stream via s_load.
__global__ __launch_bounds__(256, 2) void assign_kernel(const float* __restrict__ xn,
                                                        const float* __restrict__ xsq,
                                                        const float* __restrict__ cen,
                                                        const float* __restrict__ c2,
                                                        float* __restrict__ part,
                                                        float* __restrict__ cntpart) {
    __shared__ float accf[KC * 65];
    __shared__ float cntf[KC];
    int tid = threadIdx.x;
    for (int i = tid; i < KC * 65; i += 256) accf[i] = 0.f;
    if (tid < KC) cntf[tid] = 0.f;
    __syncthreads();

    int lane = tid & 63;
    int wv = __builtin_amdgcn_readfirstlane(tid >> 6);  // force uniformity
    int blk = blockIdx.x, b = blk >> 5;
    int pbase = b * NPTS + ((blk & 31) << 8) + wv * 64;

    LOAD_C2ROWS();

    for (int i = 0; i < 64; ++i) {
        int p = pbase + i;
        const float* xrow = xn + (size_t)p * DIM;  // wave-uniform -> s_load
        LOAD_XS(xrow);
        float xq = xsq[p];

        float dA, dB;
        DOT_SC(dA, cA);
        DOT_SC(dB, cB);
        float distA = (xq + c2A) - 2.0f * dA;
        float distB = (xq + c2B) - 2.0f * dB;

        float bd = distA; int bk = kA;
        if (distB < bd) { bd = distB; bk = kB; }   // kA < kB: first-index
#pragma unroll
        for (int mm = 1; mm <= 32; mm <<= 1) {
            float od = __shfl_xor(bd, mm, 64);
            int ok = __shfl_xor(bk, mm, 64);
            if (od < bd || (od == bd && ok < bk)) { bd = od; bk = ok; }
        }

        // accumulate: lane contributes dim=lane (f32 LDS atomics, R6-proven)
        float xv = xrow[lane];
        atomicAdd(&accf[bk * 65 + lane], xv);
        if (lane == 0) atomicAdd(&cntf[bk], 1.0f);
    }
    __syncthreads();

    float* gp = part + (size_t)blk * (KC * DIM);
    for (int i = tid; i < KC * DIM; i += 256) {
        int k = i >> 6, d = i & 63;
        gp[i] = accf[k * 65 + d];
    }
    if (tid < KC) cntpart[blk * KC + tid] = cntf[tid];
}

// One wave per (b,k): fp64 reduce of 32 f32 block partials (unchanged R6).
__global__ __launch_bounds__(256) void update_kernel(const float* __restrict__ part,
                                                     const float* __restrict__ cntpart,
                                                     float* __restrict__ cen,
                                                     float* __restrict__ c2) {
    int row = blockIdx.x * 4 + (threadIdx.x >> 6);  // b*KC + k
    int lane = threadIdx.x & 63;
    int b = row >> 7;
    int k = row & (KC - 1);

    double s = 0.0;
    float cnt = 0.f;
#pragma unroll
    for (int sub = 0; sub < BLKS_PER_B; ++sub) {
        s += (double)part[((size_t)(b * BLKS_PER_B + sub)) * (KC * DIM) + (size_t)k * DIM + lane];
        cnt += cntpart[(b * BLKS_PER_B + sub) * KC + k];
    }

    size_t idx = (size_t)row * DIM + lane;
    float old = cen[idx];
    float nc = (cnt > 0.f) ? ((float)s / cnt) : old;
    cen[idx] = nc;

    float q = nc * nc;
#pragma unroll
    for (int m = 32; m >= 1; m >>= 1) q += __shfl_xor(q, m, 64);
    if (lane == 0) c2[row] = q;
}

// Single pass: wave holds all 128 z in registers; butterfly max + sum;
// float2 stores (512B/point, full lines). No LDS.
__global__ __launch_bounds__(256, 2) void final_kernel(const float* __restrict__ xn,
                                                       const float* __restrict__ xsq,
                                                       const float* __restrict__ cen,
                                                       const float* __restrict__ c2,
                                                       float* __restrict__ soft) {
    int tid = threadIdx.x;
    int lane = tid & 63;
    int wv = __builtin_amdgcn_readfirstlane(tid >> 6);
    int blk = blockIdx.x, b = blk >> 5;
    int pbase = b * NPTS + ((blk & 31) << 8) + wv * 64;

    LOAD_C2ROWS();

    for (int i = 0; i < 64; ++i) {
        int p = pbase + i;
        const float* xrow = xn + (size_t)p * DIM;
        LOAD_XS(xrow);
        float xq = xsq[p];

        float dA, dB;
        DOT_SC(dA, cA);
        DOT_SC(dB, cB);
        float zA = -((xq + c2A) - 2.0f * dA);
        float zB = -((xq + c2B) - 2.0f * dB);

        float m = fmaxf(zA, zB);
#pragma unroll
        for (int mm = 1; mm <= 32; mm <<= 1) m = fmaxf(m, __shfl_xor(m, mm, 64));

        float eA = __expf(zA - m), eB = __expf(zB - m);
        float s = eA + eB;
#pragma unroll
        for (int mm = 1; mm <= 32; mm <<= 1) s += __shfl_xor(s, mm, 64);
        float rinv = 1.0f / s;

        ((float2*)(soft + (size_t)p * KC))[lane] = make_float2(eA * rinv, eB * rinv);
    }
}

extern "C" void kernel_launch(void* const* d_in, const int* in_sizes, int n_in,
                              void* d_out, int out_size, void* d_ws, size_t ws_size,
                              hipStream_t stream) {
    (void)in_sizes; (void)n_in; (void)out_size; (void)ws_size;
    const float* patches = (const float*)d_in[0];
    const float* gamma = (const float*)d_in[1];
    const float* beta = (const float*)d_in[2];
    float* out = (float*)d_out;

    float* ws = (float*)d_ws;
    float* xn = ws;                                   // 16,777,216 f32
    float* xsq = xn + (size_t)BATCH * NPTS * DIM;     // 262,144 f32
    float* c2 = xsq + (size_t)BATCH * NPTS;           // 4,096 f32

    float* cen = out;                                 // centers live in d_out
    float* soft = out + (size_t)BATCH * KC * DIM;
    float* part = soft;                               // 1024*8192 f32 (temp)
    float* cntpart = part + (size_t)NBLK * KC * DIM;  // 1024*128 f32 (temp)

    ln_kernel<<<BATCH * NPTS / 4, 256, 0, stream>>>(patches, gamma, beta, xn, cen, c2);
    xsq_kernel<<<BATCH * NPTS / 256, 256, 0, stream>>>(xn, xsq);

    for (int it = 0; it < NITER; ++it) {
        assign_kernel<<<NBLK, 256, 0, stream>>>(xn, xsq, cen, c2, part, cntpart);
        update_kernel<<<BATCH * KC / 4, 256, 0, stream>>>(part, cntpart, cen, c2);
    }

    final_kernel<<<NBLK, 256, 0, stream>>>(xn, xsq, cen, c2, soft);
}